// Round 1
// baseline (435.277 us; speedup 1.0000x reference)
//
#include <hip/hip_runtime.h>
#include <hip/hip_bf16.h>
#include <stdint.h>

#define T_SEQ 2048
#define HID   2048
#define NQH   16
#define NKVH  8
#define HD    128
#define QKV_N 4096   // (16 + 2*8) * 128

typedef __attribute__((ext_vector_type(8))) short short8;
typedef __attribute__((ext_vector_type(4))) float f32x4;

// ---------- helpers ----------
__device__ inline unsigned short f2bf(float f) {
  union { float f; unsigned u; } v; v.f = f;
  unsigned r = (v.u + 0x7FFFu + ((v.u >> 16) & 1u)) >> 16;
  return (unsigned short)r;
}

__device__ inline void gld16(void* lds, const void* g) {
  __builtin_amdgcn_global_load_lds(
      (const __attribute__((address_space(1))) unsigned int*)g,
      (__attribute__((address_space(3))) unsigned int*)lds, 16, 0, 0);
}

// ---------- convert fp32 -> bf16 (elementwise, 4/thread) ----------
__global__ __launch_bounds__(256) void k_cvt_bf16(const float* __restrict__ in,
                                                  unsigned short* __restrict__ out) {
  int i = (blockIdx.x * 256 + threadIdx.x) * 4;
  float4 v = *(const float4*)&in[i];
  ushort4 o;
  o.x = f2bf(v.x); o.y = f2bf(v.y); o.z = f2bf(v.z); o.w = f2bf(v.w);
  *(ushort4*)&out[i] = o;
}

// ---------- transpose fp32 [R][C] -> bf16 [C][R] ----------
__global__ __launch_bounds__(256) void k_transpose_cvt(const float* __restrict__ in,
                                                       unsigned short* __restrict__ out,
                                                       int R, int C) {
  __shared__ float tile[32][33];
  int c0 = blockIdx.x * 32, r0 = blockIdx.y * 32;
  int tx = threadIdx.x, ty = threadIdx.y;
#pragma unroll
  for (int i = 0; i < 4; i++)
    tile[ty + 8 * i][tx] = in[(size_t)(r0 + ty + 8 * i) * C + c0 + tx];
  __syncthreads();
#pragma unroll
  for (int i = 0; i < 4; i++)
    out[(size_t)(c0 + ty + 8 * i) * R + r0 + tx] = f2bf(tile[tx][ty + 8 * i]);
}

// ---------- bf16 GEMM: C[M][N] = A[M][K] * Bt[N][K]^T  (m97 structure) ----------
__global__ __launch_bounds__(256) void k_gemm_bt(const unsigned short* __restrict__ A,
                                                 const unsigned short* __restrict__ Bt,
                                                 float* __restrict__ C,
                                                 int M, int N, int K) {
  __shared__ unsigned short Als[128 * 32];
  __shared__ unsigned short Bls[128 * 32];
  int tid = threadIdx.x;
  int w = tid >> 6, l = tid & 63;
  int bm = blockIdx.y, bn = blockIdx.x;
  int m0 = bm * 128, n0 = bn * 128;
  int wr = (w >> 1) * 64, wc = (w & 1) * 64;
  int lr = l & 15, g = l >> 4;

  f32x4 acc[4][4] = {};

  // staging indices (element offsets within the 128x32 tile)
  int eo0 = w * 1024 + l * 8;
  int sr0 = eo0 >> 5, sc0 = eo0 & 31;
  int eo1 = eo0 + 512;
  int sr1 = eo1 >> 5, sc1 = eo1 & 31;

  int NT = K / 32;
  for (int t = 0; t < NT; t++) {
    int k0 = t * 32;
    gld16(&Als[w * 1024],       &A[(size_t)(m0 + sr0) * K + k0 + sc0]);
    gld16(&Als[w * 1024 + 512], &A[(size_t)(m0 + sr1) * K + k0 + sc1]);
    gld16(&Bls[w * 1024],       &Bt[(size_t)(n0 + sr0) * K + k0 + sc0]);
    gld16(&Bls[w * 1024 + 512], &Bt[(size_t)(n0 + sr1) * K + k0 + sc1]);
    __syncthreads();
    short8 af[4], bfr[4];
#pragma unroll
    for (int m = 0; m < 4; m++) af[m]  = *(const short8*)&Als[(wr + m * 16 + lr) * 32 + g * 8];
#pragma unroll
    for (int n = 0; n < 4; n++) bfr[n] = *(const short8*)&Bls[(wc + n * 16 + lr) * 32 + g * 8];
#pragma unroll
    for (int m = 0; m < 4; m++)
#pragma unroll
      for (int n = 0; n < 4; n++)
        acc[m][n] = __builtin_amdgcn_mfma_f32_16x16x32_bf16(af[m], bfr[n], acc[m][n], 0, 0, 0);
    __syncthreads();
  }

#pragma unroll
  for (int m = 0; m < 4; m++)
#pragma unroll
    for (int n = 0; n < 4; n++)
#pragma unroll
      for (int j = 0; j < 4; j++) {
        int row = m0 + wr + m * 16 + g * 4 + j;
        int col = n0 + wc + n * 16 + lr;
        C[(size_t)row * N + col] = acc[m][n][j];
      }
}

// ---------- fused per-head RMSNorm + RoPE + layout to head-major bf16 ----------
__global__ __launch_bounds__(64) void k_normrope(const float* __restrict__ qkv,
                                                 const int* __restrict__ pos_ids,
                                                 const float* __restrict__ qw,
                                                 const float* __restrict__ kw,
                                                 unsigned short* __restrict__ Qb,
                                                 unsigned short* __restrict__ Kb,
                                                 unsigned short* __restrict__ Vb) {
  int slot = blockIdx.x;  // 0..15 q heads, 16..23 k heads, 24..31 v heads
  int t = blockIdx.y;
  int l = threadIdx.x;    // 0..63
  const float* src = &qkv[(size_t)t * QKV_N + slot * HD];
  float a = src[l], b = src[l + 64];

  if (slot < 24) {
    float ss = a * a + b * b;
#pragma unroll
    for (int m = 1; m < 64; m <<= 1) ss += __shfl_xor(ss, m);
    float r = rsqrtf(ss * (1.0f / 128.0f) + 1e-6f);
    const float* nw = (slot < 16) ? qw : kw;
    a *= r * nw[l];
    b *= r * nw[l + 64];
    // RoPE (neox rotate-half): pair (l, l+64)
    float p = (float)pos_ids[t];
    float invf = exp2f(-(float)l * 0.31143075889569023f);  // log2(1e6)/64
    float ang = p * invf;
    float cs = cosf(ang), sn = sinf(ang);
    float oa = a * cs - b * sn;
    float ob = b * cs + a * sn;
    if (slot < 16) {
      const float s = 0.08838834764831845f;  // 1/sqrt(128), fold attn scale into Q
      oa *= s; ob *= s;
      size_t d = ((size_t)slot * T_SEQ + t) * HD;
      Qb[d + l] = f2bf(oa); Qb[d + 64 + l] = f2bf(ob);
    } else {
      size_t d = ((size_t)(slot - 16) * T_SEQ + t) * HD;
      Kb[d + l] = f2bf(oa); Kb[d + 64 + l] = f2bf(ob);
    }
  } else {
    size_t d = ((size_t)(slot - 24) * T_SEQ + t) * HD;
    Vb[d + l] = f2bf(a); Vb[d + 64 + l] = f2bf(b);
  }
}

// ---------- causal GQA flash attention ----------
// grid: (T/64, NQH), block: 256 (4 waves, 16 q-rows each)
__global__ __launch_bounds__(256) void k_attn(const unsigned short* __restrict__ Qb,
                                              const unsigned short* __restrict__ Kb,
                                              const unsigned short* __restrict__ Vb,
                                              unsigned short* __restrict__ Ob) {
  __shared__ unsigned short Klds[64 * 136];   // [kv][d], padded
  __shared__ unsigned short Vtlds[128 * 72];  // [d][kv], padded
  __shared__ unsigned short Plds[4 * 16 * 72];// per-wave P [16][64+pad]

  int qb = blockIdx.x, h = blockIdx.y, kvh = h >> 1;
  int tid = threadIdx.x, w = tid >> 6, l = tid & 63;
  int lr = l & 15, g = l >> 4;
  int qr0 = qb * 64 + w * 16;

  // Q fragments (A operand), scale already folded in
  short8 qf[4];
  const unsigned short* qrow = &Qb[((size_t)h * T_SEQ + qr0 + lr) * HD];
#pragma unroll
  for (int c = 0; c < 4; c++) qf[c] = *(const short8*)&qrow[c * 32 + g * 8];

  f32x4 acc[8] = {};
  float mrow[4], lsum[4];
#pragma unroll
  for (int j = 0; j < 4; j++) { mrow[j] = -1e30f; lsum[j] = 0.0f; }

  int NTk = qb + 1;
  for (int kt = 0; kt < NTk; kt++) {
    int kv0 = kt * 64;
    __syncthreads();  // prior-tile reads finished
    // stage K [64][128] and V^T [128][64]
#pragma unroll
    for (int it = 0; it < 4; it++) {
      int ch = tid + it * 256;          // 0..1023 chunks of 8 elems
      int row = ch >> 4, col = (ch & 15) * 8;
      short8 kv = *(const short8*)&Kb[((size_t)kvh * T_SEQ + kv0 + row) * HD + col];
      *(short8*)&Klds[row * 136 + col] = kv;
      short8 vv = *(const short8*)&Vb[((size_t)kvh * T_SEQ + kv0 + row) * HD + col];
#pragma unroll
      for (int i = 0; i < 8; i++)
        Vtlds[(col + i) * 72 + row] = (unsigned short)vv[i];
    }
    __syncthreads();

    // S = Q K^T  (16 x 64 per wave)
    f32x4 s[4];
#pragma unroll
    for (int ct = 0; ct < 4; ct++) {
      f32x4 sv = {};
#pragma unroll
      for (int dc = 0; dc < 4; dc++) {
        short8 kf = *(const short8*)&Klds[(ct * 16 + lr) * 136 + dc * 32 + g * 8];
        sv = __builtin_amdgcn_mfma_f32_16x16x32_bf16(qf[dc], kf, sv, 0, 0, 0);
      }
      s[ct] = sv;
    }

    // causal mask
#pragma unroll
    for (int ct = 0; ct < 4; ct++)
#pragma unroll
      for (int j = 0; j < 4; j++) {
        int qr = qr0 + g * 4 + j;
        int kc = kv0 + ct * 16 + lr;
        if (kc > qr) s[ct][j] = -1e30f;
      }

    // online softmax
    float pr[4][4];
    float sc[4];
#pragma unroll
    for (int j = 0; j < 4; j++) {
      float mx = fmaxf(fmaxf(s[0][j], s[1][j]), fmaxf(s[2][j], s[3][j]));
#pragma unroll
      for (int msk = 1; msk < 16; msk <<= 1) mx = fmaxf(mx, __shfl_xor(mx, msk));
      float mnew = fmaxf(mrow[j], mx);
      sc[j] = __expf(mrow[j] - mnew);
#pragma unroll
      for (int ct = 0; ct < 4; ct++) pr[ct][j] = __expf(s[ct][j] - mnew);
      float su = pr[0][j] + pr[1][j] + pr[2][j] + pr[3][j];
#pragma unroll
      for (int msk = 1; msk < 16; msk <<= 1) su += __shfl_xor(su, msk);
      lsum[j] = lsum[j] * sc[j] + su;
      mrow[j] = mnew;
    }
    // rescale accumulator
#pragma unroll
    for (int n = 0; n < 8; n++)
#pragma unroll
      for (int j = 0; j < 4; j++) acc[n][j] *= sc[j];

    // P -> LDS (per-wave private)
#pragma unroll
    for (int ct = 0; ct < 4; ct++)
#pragma unroll
      for (int j = 0; j < 4; j++)
        Plds[w * 1152 + (g * 4 + j) * 72 + ct * 16 + lr] = f2bf(pr[ct][j]);

    // PV: acc += P[16x64] * V[64x128]
    short8 pa0 = *(const short8*)&Plds[w * 1152 + lr * 72 + g * 8];
    short8 pa1 = *(const short8*)&Plds[w * 1152 + lr * 72 + 32 + g * 8];
#pragma unroll
    for (int n = 0; n < 8; n++) {
      short8 v0 = *(const short8*)&Vtlds[(n * 16 + lr) * 72 + g * 8];
      short8 v1 = *(const short8*)&Vtlds[(n * 16 + lr) * 72 + 32 + g * 8];
      acc[n] = __builtin_amdgcn_mfma_f32_16x16x32_bf16(pa0, v0, acc[n], 0, 0, 0);
      acc[n] = __builtin_amdgcn_mfma_f32_16x16x32_bf16(pa1, v1, acc[n], 0, 0, 0);
    }
  }

  // epilogue: O[t][h*128 + d]
#pragma unroll
  for (int n = 0; n < 8; n++)
#pragma unroll
    for (int j = 0; j < 4; j++) {
      int row = qr0 + g * 4 + j;
      int col = h * HD + n * 16 + lr;
      Ob[(size_t)row * HID + col] = f2bf(acc[n][j] / lsum[j]);
    }
}

// ---------- launcher ----------
extern "C" void kernel_launch(void* const* d_in, const int* in_sizes, int n_in,
                              void* d_out, int out_size, void* d_ws, size_t ws_size,
                              hipStream_t stream) {
  const float* x      = (const float*)d_in[0];
  const int*   pos    = (const int*)d_in[1];
  const float* w_qkv  = (const float*)d_in[2];
  const float* w_o    = (const float*)d_in[3];
  const float* qnw    = (const float*)d_in[4];
  const float* knw    = (const float*)d_in[5];
  float* out = (float*)d_out;

  char* ws = (char*)d_ws;
  const size_t MB = 1024 * 1024;
  unsigned short* x_bf   = (unsigned short*)(ws + 0);        // 8 MB  [2048][2048]
  unsigned short* Ob     = (unsigned short*)(ws + 0);        // reuses x_bf after GEMM1
  unsigned short* wqkv_t = (unsigned short*)(ws + 8 * MB);   // 16 MB [4096][2048]
  unsigned short* wo_t   = (unsigned short*)(ws + 24 * MB);  // 8 MB  [2048][2048]
  float*          qkv    = (float*)(ws + 32 * MB);           // 32 MB [2048][4096]
  unsigned short* Qb     = (unsigned short*)(ws + 64 * MB);  // 8 MB  [16][2048][128]
  unsigned short* Kb     = (unsigned short*)(ws + 72 * MB);  // 4 MB  [8][2048][128]
  unsigned short* Vb     = (unsigned short*)(ws + 76 * MB);  // 4 MB  [8][2048][128]

  // 1. convert x to bf16
  k_cvt_bf16<<<(T_SEQ * HID) / 1024, 256, 0, stream>>>(x, x_bf);
  // 2. transpose+convert weights
  k_transpose_cvt<<<dim3(QKV_N / 32, HID / 32), dim3(32, 8), 0, stream>>>(w_qkv, wqkv_t, HID, QKV_N);
  k_transpose_cvt<<<dim3(HID / 32, HID / 32), dim3(32, 8), 0, stream>>>(w_o, wo_t, HID, HID);
  // 3. QKV GEMM: [2048][2048] x [2048][4096] -> fp32
  k_gemm_bt<<<dim3(QKV_N / 128, T_SEQ / 128), 256, 0, stream>>>(x_bf, wqkv_t, qkv, T_SEQ, QKV_N, HID);
  // 4. RMSNorm + RoPE + head-major bf16 Q/K/V
  k_normrope<<<dim3(32, T_SEQ), 64, 0, stream>>>(qkv, pos, qnw, knw, Qb, Kb, Vb);
  // 5. causal GQA flash attention -> Ob bf16 [2048][2048]
  k_attn<<<dim3(T_SEQ / 64, NQH), 256, 0, stream>>>(Qb, Kb, Vb, Ob);
  // 6. output projection -> d_out fp32
  k_gemm_bt<<<dim3(HID / 128, T_SEQ / 128), 256, 0, stream>>>(Ob, wo_t, out, T_SEQ, HID, HID);
}

// Round 2
// 308.919 us; speedup vs baseline: 1.4090x; 1.4090x over previous
//
#include <hip/hip_runtime.h>
#include <hip/hip_bf16.h>
#include <stdint.h>

#define T_SEQ 2048
#define HID   2048
#define NQH   16
#define NKVH  8
#define HD    128
#define QKV_N 4096   // (16 + 2*8) * 128

typedef __attribute__((ext_vector_type(8))) short short8;
typedef __attribute__((ext_vector_type(4))) float f32x4;

// ---------- helpers ----------
__device__ inline unsigned short f2bf(float f) {
  union { float f; unsigned u; } v; v.f = f;
  unsigned r = (v.u + 0x7FFFu + ((v.u >> 16) & 1u)) >> 16;
  return (unsigned short)r;
}

__device__ inline void gld16(void* lds, const void* g) {
  __builtin_amdgcn_global_load_lds(
      (const __attribute__((address_space(1))) unsigned int*)g,
      (__attribute__((address_space(3))) unsigned int*)lds, 16, 0, 0);
}

// ---------- convert fp32 -> bf16 (elementwise, 4/thread) ----------
__global__ __launch_bounds__(256) void k_cvt_bf16(const float* __restrict__ in,
                                                  unsigned short* __restrict__ out) {
  int i = (blockIdx.x * 256 + threadIdx.x) * 4;
  float4 v = *(const float4*)&in[i];
  ushort4 o;
  o.x = f2bf(v.x); o.y = f2bf(v.y); o.z = f2bf(v.z); o.w = f2bf(v.w);
  *(ushort4*)&out[i] = o;
}

// ---------- transpose fp32 [R][C] -> bf16 [C][R] ----------
__global__ __launch_bounds__(256) void k_transpose_cvt(const float* __restrict__ in,
                                                       unsigned short* __restrict__ out,
                                                       int R, int C) {
  __shared__ float tile[32][33];
  int c0 = blockIdx.x * 32, r0 = blockIdx.y * 32;
  int tx = threadIdx.x, ty = threadIdx.y;
#pragma unroll
  for (int i = 0; i < 4; i++)
    tile[ty + 8 * i][tx] = in[(size_t)(r0 + ty + 8 * i) * C + c0 + tx];
  __syncthreads();
#pragma unroll
  for (int i = 0; i < 4; i++)
    out[(size_t)(c0 + ty + 8 * i) * R + r0 + tx] = f2bf(tile[tx][ty + 8 * i]);
}

// ---------- bf16 GEMM: C[M][N] = A[M][K] * Bt[N][K]^T  (m97 structure) ----------
__global__ __launch_bounds__(256) void k_gemm_bt(const unsigned short* __restrict__ A,
                                                 const unsigned short* __restrict__ Bt,
                                                 float* __restrict__ C,
                                                 int M, int N, int K) {
  __shared__ unsigned short Als[128 * 32];
  __shared__ unsigned short Bls[128 * 32];
  int tid = threadIdx.x;
  int w = tid >> 6, l = tid & 63;
  int bm = blockIdx.y, bn = blockIdx.x;
  int m0 = bm * 128, n0 = bn * 128;
  int wr = (w >> 1) * 64, wc = (w & 1) * 64;
  int lr = l & 15, g = l >> 4;

  f32x4 acc[4][4] = {};

  int eo0 = w * 1024 + l * 8;
  int sr0 = eo0 >> 5, sc0 = eo0 & 31;
  int eo1 = eo0 + 512;
  int sr1 = eo1 >> 5, sc1 = eo1 & 31;

  int NT = K / 32;
  for (int t = 0; t < NT; t++) {
    int k0 = t * 32;
    gld16(&Als[w * 1024],       &A[(size_t)(m0 + sr0) * K + k0 + sc0]);
    gld16(&Als[w * 1024 + 512], &A[(size_t)(m0 + sr1) * K + k0 + sc1]);
    gld16(&Bls[w * 1024],       &Bt[(size_t)(n0 + sr0) * K + k0 + sc0]);
    gld16(&Bls[w * 1024 + 512], &Bt[(size_t)(n0 + sr1) * K + k0 + sc1]);
    __syncthreads();
    short8 af[4], bfr[4];
#pragma unroll
    for (int m = 0; m < 4; m++) af[m]  = *(const short8*)&Als[(wr + m * 16 + lr) * 32 + g * 8];
#pragma unroll
    for (int n = 0; n < 4; n++) bfr[n] = *(const short8*)&Bls[(wc + n * 16 + lr) * 32 + g * 8];
#pragma unroll
    for (int m = 0; m < 4; m++)
#pragma unroll
      for (int n = 0; n < 4; n++)
        acc[m][n] = __builtin_amdgcn_mfma_f32_16x16x32_bf16(af[m], bfr[n], acc[m][n], 0, 0, 0);
    __syncthreads();
  }

#pragma unroll
  for (int m = 0; m < 4; m++)
#pragma unroll
    for (int n = 0; n < 4; n++)
#pragma unroll
      for (int j = 0; j < 4; j++) {
        int row = m0 + wr + m * 16 + g * 4 + j;
        int col = n0 + wc + n * 16 + lr;
        C[(size_t)row * N + col] = acc[m][n][j];
      }
}

// ---------- fused per-head RMSNorm + RoPE + layout to head-major bf16 ----------
__global__ __launch_bounds__(64) void k_normrope(const float* __restrict__ qkv,
                                                 const int* __restrict__ pos_ids,
                                                 const float* __restrict__ qw,
                                                 const float* __restrict__ kw,
                                                 unsigned short* __restrict__ Qb,
                                                 unsigned short* __restrict__ Kb,
                                                 unsigned short* __restrict__ Vb) {
  int slot = blockIdx.x;  // 0..15 q heads, 16..23 k heads, 24..31 v heads
  int t = blockIdx.y;
  int l = threadIdx.x;    // 0..63
  const float* src = &qkv[(size_t)t * QKV_N + slot * HD];
  float a = src[l], b = src[l + 64];

  if (slot < 24) {
    float ss = a * a + b * b;
#pragma unroll
    for (int m = 1; m < 64; m <<= 1) ss += __shfl_xor(ss, m);
    float r = rsqrtf(ss * (1.0f / 128.0f) + 1e-6f);
    const float* nw = (slot < 16) ? qw : kw;
    a *= r * nw[l];
    b *= r * nw[l + 64];
    float p = (float)pos_ids[t];
    float invf = exp2f(-(float)l * 0.31143075889569023f);  // log2(1e6)/64
    float ang = p * invf;
    float cs = cosf(ang), sn = sinf(ang);
    float oa = a * cs - b * sn;
    float ob = b * cs + a * sn;
    if (slot < 16) {
      const float s = 0.08838834764831845f;  // 1/sqrt(128), fold attn scale into Q
      oa *= s; ob *= s;
      size_t d = ((size_t)slot * T_SEQ + t) * HD;
      Qb[d + l] = f2bf(oa); Qb[d + 64 + l] = f2bf(ob);
    } else {
      size_t d = ((size_t)(slot - 16) * T_SEQ + t) * HD;
      Kb[d + l] = f2bf(oa); Kb[d + 64 + l] = f2bf(ob);
    }
  } else {
    size_t d = ((size_t)(slot - 24) * T_SEQ + t) * HD;
    Vb[d + l] = f2bf(a); Vb[d + 64 + l] = f2bf(b);
  }
}

// ---------- causal GQA flash attention, v2 ----------
// Work pairing: block x = i (0..15) handles q-tiles i (waves 0-3) and 31-i
// (waves 4-7); both strips share one K/V staging pass over kv tiles 0..31-i.
// Every block does exactly 33 tile-computations -> uniform load.
// grid: (16, NQH), block: 512 (8 waves, 16 q-rows each)
__global__ __launch_bounds__(512) void k_attn(const unsigned short* __restrict__ Qb,
                                              const unsigned short* __restrict__ Kb,
                                              const unsigned short* __restrict__ Vb,
                                              unsigned short* __restrict__ Ob) {
  __shared__ unsigned short Klds[64 * 136];   // [kv][d], padded (+8)
  __shared__ unsigned short Vt[128 * 64];     // [d][kv], XOR-swizzled
  __shared__ unsigned short Plds[8 * 16 * 72];// per-wave P [16][64+pad]

  int pairIdx = blockIdx.x;       // 0..15
  int h = blockIdx.y, kvh = h >> 1;
  int tid = threadIdx.x, w = tid >> 6, l = tid & 63;
  int lr = l & 15, g = l >> 4;
  int qbA = pairIdx, qbB = 31 - pairIdx;
  int qbw = (w < 4) ? qbA : qbB;  // this wave's q-tile
  int qr0 = qbw * 64 + (w & 3) * 16;

  // Q fragments (A operand), attn scale already folded in
  short8 qf[4];
  const unsigned short* qrow = &Qb[((size_t)h * T_SEQ + qr0 + lr) * HD];
#pragma unroll
  for (int c = 0; c < 4; c++) qf[c] = *(const short8*)&qrow[c * 32 + g * 8];

  f32x4 acc[8] = {};
  float mrow[4], lsum[4];
#pragma unroll
  for (int j = 0; j < 4; j++) { mrow[j] = -1e30f; lsum[j] = 0.0f; }

  int NT = qbB + 1;
  for (int kt = 0; kt < NT; kt++) {
    int kv0 = kt * 64;
    __syncthreads();  // prior-tile LDS reads finished
    // stage K [64][128] row-major and V as swizzled V^T [128][64]
#pragma unroll
    for (int it = 0; it < 2; it++) {
      int ch = tid + it * 512;          // 0..1023 chunks of 8 elems
      int row = ch >> 4, c = ch & 15, col = c * 8;
      short8 kv = *(const short8*)&Kb[((size_t)kvh * T_SEQ + kv0 + row) * HD + col];
      *(short8*)&Klds[row * 136 + col] = kv;
      short8 vv = *(const short8*)&Vb[((size_t)kvh * T_SEQ + kv0 + row) * HD + col];
#pragma unroll
      for (int i = 0; i < 8; i++) {
        int d = col + i;
        int s = (d ^ (d >> 3)) & 7;
        Vt[d * 64 + (row ^ (s << 3))] = (unsigned short)vv[i];
      }
    }
    __syncthreads();

    if (kt <= qbw) {
      // S = Q K^T  (16 x 64)
      f32x4 s[4];
#pragma unroll
      for (int ct = 0; ct < 4; ct++) {
        f32x4 sv = {};
#pragma unroll
        for (int dc = 0; dc < 4; dc++) {
          short8 kf = *(const short8*)&Klds[(ct * 16 + lr) * 136 + dc * 32 + g * 8];
          sv = __builtin_amdgcn_mfma_f32_16x16x32_bf16(qf[dc], kf, sv, 0, 0, 0);
        }
        s[ct] = sv;
      }

      // causal mask only on the diagonal tile
      if (kt == qbw) {
#pragma unroll
        for (int ct = 0; ct < 4; ct++)
#pragma unroll
          for (int j = 0; j < 4; j++) {
            int qr = qr0 + g * 4 + j;
            int kc = kv0 + ct * 16 + lr;
            if (kc > qr) s[ct][j] = -1e30f;
          }
      }

      // online softmax
      float pr[4][4];
      float sc[4];
#pragma unroll
      for (int j = 0; j < 4; j++) {
        float mx = fmaxf(fmaxf(s[0][j], s[1][j]), fmaxf(s[2][j], s[3][j]));
#pragma unroll
        for (int msk = 1; msk < 16; msk <<= 1) mx = fmaxf(mx, __shfl_xor(mx, msk));
        float mnew = fmaxf(mrow[j], mx);
        sc[j] = __expf(mrow[j] - mnew);
#pragma unroll
        for (int ct = 0; ct < 4; ct++) pr[ct][j] = __expf(s[ct][j] - mnew);
        float su = pr[0][j] + pr[1][j] + pr[2][j] + pr[3][j];
#pragma unroll
        for (int msk = 1; msk < 16; msk <<= 1) su += __shfl_xor(su, msk);
        lsum[j] = lsum[j] * sc[j] + su;
        mrow[j] = mnew;
      }
#pragma unroll
      for (int n = 0; n < 8; n++)
#pragma unroll
        for (int j = 0; j < 4; j++) acc[n][j] *= sc[j];

      // P -> LDS (per-wave private)
#pragma unroll
      for (int ct = 0; ct < 4; ct++)
#pragma unroll
        for (int j = 0; j < 4; j++)
          Plds[w * 1152 + (g * 4 + j) * 72 + ct * 16 + lr] = f2bf(pr[ct][j]);

      // PV: acc += P[16x64] * V[64x128]
      short8 pa0 = *(const short8*)&Plds[w * 1152 + lr * 72 + g * 8];
      short8 pa1 = *(const short8*)&Plds[w * 1152 + lr * 72 + 32 + g * 8];
#pragma unroll
      for (int n = 0; n < 8; n++) {
        int d0 = n * 16 + lr;
        int s0 = (d0 ^ (d0 >> 3)) & 7;
        short8 v0 = *(const short8*)&Vt[d0 * 64 + ((g ^ s0) << 3)];
        short8 v1 = *(const short8*)&Vt[d0 * 64 + (((4 + g) ^ s0) << 3)];
        acc[n] = __builtin_amdgcn_mfma_f32_16x16x32_bf16(pa0, v0, acc[n], 0, 0, 0);
        acc[n] = __builtin_amdgcn_mfma_f32_16x16x32_bf16(pa1, v1, acc[n], 0, 0, 0);
      }
    }
  }

  // epilogue: O[t][h*128 + d]
#pragma unroll
  for (int n = 0; n < 8; n++)
#pragma unroll
    for (int j = 0; j < 4; j++) {
      int row = qr0 + g * 4 + j;
      int col = h * HD + n * 16 + lr;
      Ob[(size_t)row * HID + col] = f2bf(acc[n][j] / lsum[j]);
    }
}

// ---------- launcher ----------
extern "C" void kernel_launch(void* const* d_in, const int* in_sizes, int n_in,
                              void* d_out, int out_size, void* d_ws, size_t ws_size,
                              hipStream_t stream) {
  const float* x      = (const float*)d_in[0];
  const int*   pos    = (const int*)d_in[1];
  const float* w_qkv  = (const float*)d_in[2];
  const float* w_o    = (const float*)d_in[3];
  const float* qnw    = (const float*)d_in[4];
  const float* knw    = (const float*)d_in[5];
  float* out = (float*)d_out;

  char* ws = (char*)d_ws;
  const size_t MB = 1024 * 1024;
  unsigned short* x_bf   = (unsigned short*)(ws + 0);        // 8 MB  [2048][2048]
  unsigned short* Ob     = (unsigned short*)(ws + 0);        // reuses x_bf after GEMM1
  unsigned short* wqkv_t = (unsigned short*)(ws + 8 * MB);   // 16 MB [4096][2048]
  unsigned short* wo_t   = (unsigned short*)(ws + 24 * MB);  // 8 MB  [2048][2048]
  float*          qkv    = (float*)(ws + 32 * MB);           // 32 MB [2048][4096]
  unsigned short* Qb     = (unsigned short*)(ws + 64 * MB);  // 8 MB  [16][2048][128]
  unsigned short* Kb     = (unsigned short*)(ws + 72 * MB);  // 4 MB  [8][2048][128]
  unsigned short* Vb     = (unsigned short*)(ws + 76 * MB);  // 4 MB  [8][2048][128]

  k_cvt_bf16<<<(T_SEQ * HID) / 1024, 256, 0, stream>>>(x, x_bf);
  k_transpose_cvt<<<dim3(QKV_N / 32, HID / 32), dim3(32, 8), 0, stream>>>(w_qkv, wqkv_t, HID, QKV_N);
  k_transpose_cvt<<<dim3(HID / 32, HID / 32), dim3(32, 8), 0, stream>>>(w_o, wo_t, HID, HID);
  k_gemm_bt<<<dim3(QKV_N / 128, T_SEQ / 128), 256, 0, stream>>>(x_bf, wqkv_t, qkv, T_SEQ, QKV_N, HID);
  k_normrope<<<dim3(32, T_SEQ), 64, 0, stream>>>(qkv, pos, qnw, knw, Qb, Kb, Vb);
  k_attn<<<dim3(16, NQH), 512, 0, stream>>>(Qb, Kb, Vb, Ob);
  k_gemm_bt<<<dim3(HID / 128, T_SEQ / 128), 256, 0, stream>>>(Ob, wo_t, out, T_SEQ, HID, HID);
}

// Round 4
// 302.474 us; speedup vs baseline: 1.4391x; 1.0213x over previous
//
#include <hip/hip_runtime.h>
#include <hip/hip_bf16.h>
#include <stdint.h>

#define T_SEQ 2048
#define HID   2048
#define NQH   16
#define NKVH  8
#define HD    128
#define QKV_N 4096   // (16 + 2*8) * 128

typedef __attribute__((ext_vector_type(8))) short short8;
typedef __attribute__((ext_vector_type(4))) float f32x4;

// ---------- helpers ----------
__device__ inline unsigned short f2bf(float f) {
  union { float f; unsigned u; } v; v.f = f;
  unsigned r = (v.u + 0x7FFFu + ((v.u >> 16) & 1u)) >> 16;
  return (unsigned short)r;
}

__device__ inline void gld16(void* lds, const void* g) {
  __builtin_amdgcn_global_load_lds(
      (const __attribute__((address_space(1))) unsigned int*)g,
      (__attribute__((address_space(3))) unsigned int*)lds, 16, 0, 0);
}

// ---------- convert fp32 -> bf16 (elementwise, 4/thread) ----------
__global__ __launch_bounds__(256) void k_cvt_bf16(const float* __restrict__ in,
                                                  unsigned short* __restrict__ out) {
  int i = (blockIdx.x * 256 + threadIdx.x) * 4;
  float4 v = *(const float4*)&in[i];
  ushort4 o;
  o.x = f2bf(v.x); o.y = f2bf(v.y); o.z = f2bf(v.z); o.w = f2bf(v.w);
  *(ushort4*)&out[i] = o;
}

// ---------- transpose fp32 [R][C] -> bf16 [C][R] ----------
__global__ __launch_bounds__(256) void k_transpose_cvt(const float* __restrict__ in,
                                                       unsigned short* __restrict__ out,
                                                       int R, int C) {
  __shared__ float tile[32][33];
  int c0 = blockIdx.x * 32, r0 = blockIdx.y * 32;
  int tx = threadIdx.x, ty = threadIdx.y;
#pragma unroll
  for (int i = 0; i < 4; i++)
    tile[ty + 8 * i][tx] = in[(size_t)(r0 + ty + 8 * i) * C + c0 + tx];
  __syncthreads();
#pragma unroll
  for (int i = 0; i < 4; i++)
    out[(size_t)(c0 + ty + 8 * i) * R + r0 + tx] = f2bf(tile[tx][ty + 8 * i]);
}

// ---------- bf16 GEMM: C[M][N] = A[M][K] * Bt[N][K]^T  (m97 structure) ----------
__global__ __launch_bounds__(256) void k_gemm_bt(const unsigned short* __restrict__ A,
                                                 const unsigned short* __restrict__ Bt,
                                                 float* __restrict__ C,
                                                 int M, int N, int K) {
  __shared__ unsigned short Als[128 * 32];
  __shared__ unsigned short Bls[128 * 32];
  int tid = threadIdx.x;
  int w = tid >> 6, l = tid & 63;
  int bm = blockIdx.y, bn = blockIdx.x;
  int m0 = bm * 128, n0 = bn * 128;
  int wr = (w >> 1) * 64, wc = (w & 1) * 64;
  int lr = l & 15, g = l >> 4;

  f32x4 acc[4][4] = {};

  int eo0 = w * 1024 + l * 8;
  int sr0 = eo0 >> 5, sc0 = eo0 & 31;
  int eo1 = eo0 + 512;
  int sr1 = eo1 >> 5, sc1 = eo1 & 31;

  int NT = K / 32;
  for (int t = 0; t < NT; t++) {
    int k0 = t * 32;
    gld16(&Als[w * 1024],       &A[(size_t)(m0 + sr0) * K + k0 + sc0]);
    gld16(&Als[w * 1024 + 512], &A[(size_t)(m0 + sr1) * K + k0 + sc1]);
    gld16(&Bls[w * 1024],       &Bt[(size_t)(n0 + sr0) * K + k0 + sc0]);
    gld16(&Bls[w * 1024 + 512], &Bt[(size_t)(n0 + sr1) * K + k0 + sc1]);
    __syncthreads();
    short8 af[4], bfr[4];
#pragma unroll
    for (int m = 0; m < 4; m++) af[m]  = *(const short8*)&Als[(wr + m * 16 + lr) * 32 + g * 8];
#pragma unroll
    for (int n = 0; n < 4; n++) bfr[n] = *(const short8*)&Bls[(wc + n * 16 + lr) * 32 + g * 8];
#pragma unroll
    for (int m = 0; m < 4; m++)
#pragma unroll
      for (int n = 0; n < 4; n++)
        acc[m][n] = __builtin_amdgcn_mfma_f32_16x16x32_bf16(af[m], bfr[n], acc[m][n], 0, 0, 0);
    __syncthreads();
  }

#pragma unroll
  for (int m = 0; m < 4; m++)
#pragma unroll
    for (int n = 0; n < 4; n++)
#pragma unroll
      for (int j = 0; j < 4; j++) {
        int row = m0 + wr + m * 16 + g * 4 + j;
        int col = n0 + wc + n * 16 + lr;
        C[(size_t)row * N + col] = acc[m][n][j];
      }
}

// ---------- fused per-head RMSNorm + RoPE (Q and K heads only) ----------
// K is stored with the per-row XOR swizzle d' = d ^ ((t&7)<<3) so that the
// attention kernel can global_load_lds it linearly and read MFMA fragments
// conflict-free. (Permutes 16B blocks within each 256B row: coalescing intact.)
__global__ __launch_bounds__(64) void k_normrope(const float* __restrict__ qkv,
                                                 const int* __restrict__ pos_ids,
                                                 const float* __restrict__ qw,
                                                 const float* __restrict__ kw,
                                                 unsigned short* __restrict__ Qb,
                                                 unsigned short* __restrict__ Kb) {
  int slot = blockIdx.x;  // 0..15 q heads, 16..23 k heads
  int t = blockIdx.y;
  int l = threadIdx.x;    // 0..63
  const float* src = &qkv[(size_t)t * QKV_N + slot * HD];
  float a = src[l], b = src[l + 64];

  float ss = a * a + b * b;
#pragma unroll
  for (int m = 1; m < 64; m <<= 1) ss += __shfl_xor(ss, m);
  float r = rsqrtf(ss * (1.0f / 128.0f) + 1e-6f);
  const float* nw = (slot < 16) ? qw : kw;
  a *= r * nw[l];
  b *= r * nw[l + 64];
  float p = (float)pos_ids[t];
  float invf = exp2f(-(float)l * 0.31143075889569023f);  // log2(1e6)/64
  float ang = p * invf;
  float cs = cosf(ang), sn = sinf(ang);
  float oa = a * cs - b * sn;
  float ob = b * cs + a * sn;
  if (slot < 16) {
    const float s = 0.08838834764831845f;  // 1/sqrt(128), fold attn scale into Q
    oa *= s; ob *= s;
    size_t d = ((size_t)slot * T_SEQ + t) * HD;
    Qb[d + l] = f2bf(oa); Qb[d + 64 + l] = f2bf(ob);
  } else {
    size_t d = ((size_t)(slot - 16) * T_SEQ + t) * HD;
    int sw = (t & 7) << 3;
    Kb[d + (l ^ sw)] = f2bf(oa); Kb[d + ((l + 64) ^ sw)] = f2bf(ob);
  }
}

// ---------- V: cvt + transpose + swizzle straight from the fp32 qkv buffer ----------
// Output layout: Vtg[kvh][blk][d][kv'] , kv' block-index = (kv>>3) ^ (d&7),
// i.e. the exact LDS image attention wants, so staging is a linear gld16 copy.
__global__ __launch_bounds__(256) void k_vt(const float* __restrict__ qkv,
                                            unsigned short* __restrict__ Vtg) {
  __shared__ unsigned short t[64 * 136];
  int kvh = blockIdx.y, blk = blockIdx.x;
  int tid = threadIdx.x;
  const float* src = &qkv[(size_t)(blk * 64) * QKV_N + (24 + kvh) * HD];
#pragma unroll
  for (int r = 0; r < 8; r++) {     // 2048 chunks of 4 floats = full 64x128 tile
    int c = tid + r * 256;
    int row = c >> 5, col = (c & 31) * 4;
    float4 v = *(const float4*)&src[(size_t)row * QKV_N + col];
    ushort4 o;
    o.x = f2bf(v.x); o.y = f2bf(v.y); o.z = f2bf(v.z); o.w = f2bf(v.w);
    *(ushort4*)&t[row * 136 + col] = o;
  }
  __syncthreads();
  unsigned short* dst = &Vtg[((size_t)kvh * 32 + blk) * 8192];
#pragma unroll
  for (int r = 0; r < 4; r++) {
    int c = tid + r * 256;           // 1024 chunks of 8 kv
    int d = c >> 3, kb = c & 7;
    short8 v;
#pragma unroll
    for (int i = 0; i < 8; i++) v[i] = t[(kb * 8 + i) * 136 + d];
    *(short8*)&dst[d * 64 + ((kb ^ (d & 7)) << 3)] = v;
  }
}

// ---------- causal GQA flash attention, v3 ----------
// 512 blocks (flat): qb = 31 - bid>>4 (heavy tiles dispatched first), h = bid&15.
// 4 waves x 16 q-rows. Double-buffered K/V staged via global_load_lds from
// pre-swizzled global layouts; counted vmcnt(8); raw s_barrier (no vmcnt-0 drain).
__global__ __launch_bounds__(256, 2) void k_attn(const unsigned short* __restrict__ Qb,
                                                 const unsigned short* __restrict__ Kb,
                                                 const unsigned short* __restrict__ Vtg,
                                                 unsigned short* __restrict__ Ob) {
  __shared__ unsigned short Klds[2][64 * 128];
  __shared__ unsigned short Vt[2][64 * 128];
  __shared__ unsigned short Plds[4][16 * 72];

  int bid = blockIdx.x;
  int qb = 31 - (bid >> 4);
  int h = bid & 15, kvh = h >> 1;
  int tid = threadIdx.x, w = tid >> 6, l = tid & 63;
  int lr = l & 15, g = l >> 4;
  int qr0 = qb * 64 + w * 16;

  // Q fragments (A operand), attn scale folded in
  short8 qf[4];
  const unsigned short* qrow = &Qb[((size_t)h * T_SEQ + qr0 + lr) * HD];
#pragma unroll
  for (int c = 0; c < 4; c++) qf[c] = *(const short8*)&qrow[c * 32 + g * 8];

  f32x4 acc[8] = {};
  float mrow[4], lsum[4];
#pragma unroll
  for (int j = 0; j < 4; j++) { mrow[j] = -1e30f; lsum[j] = 0.0f; }

  const unsigned short* Ksrc = &Kb[(size_t)kvh * T_SEQ * HD];
  const unsigned short* Vsrc = &Vtg[(size_t)kvh * 32 * 8192];

#define STAGE(bi, kt) do {                                          \
    const unsigned short* ks_ = Ksrc + (size_t)(kt) * 8192;         \
    const unsigned short* vs_ = Vsrc + (size_t)(kt) * 8192;         \
    _Pragma("unroll")                                               \
    for (int r_ = 0; r_ < 4; r_++) {                                \
      int cb_ = r_ * 256 + w * 64;                                  \
      gld16(&Klds[bi][cb_ * 8], ks_ + (size_t)(cb_ + l) * 8);       \
      gld16(&Vt[bi][cb_ * 8],   vs_ + (size_t)(cb_ + l) * 8);       \
    }                                                               \
  } while (0)

  int NT = qb + 1;
  STAGE(0, 0);
  for (int kt = 0; kt < NT; kt++) {
    int bi = kt & 1;
    if (kt + 1 < NT) {
      STAGE(bi ^ 1, kt + 1);
      asm volatile("s_waitcnt vmcnt(8)" ::: "memory");
    } else {
      asm volatile("s_waitcnt vmcnt(0)" ::: "memory");
    }
    __builtin_amdgcn_s_barrier();
    __builtin_amdgcn_sched_barrier(0);

    int kv0 = kt * 64;
    // S = Q K^T  (16 x 64)
    f32x4 s[4];
    __builtin_amdgcn_s_setprio(1);
#pragma unroll
    for (int ct = 0; ct < 4; ct++) {
      f32x4 sv = {};
#pragma unroll
      for (int dc = 0; dc < 4; dc++) {
        int dsw = (dc * 32 + g * 8) ^ ((lr & 7) << 3);
        short8 kf = *(const short8*)&Klds[bi][(ct * 16 + lr) * 128 + dsw];
        sv = __builtin_amdgcn_mfma_f32_16x16x32_bf16(qf[dc], kf, sv, 0, 0, 0);
      }
      s[ct] = sv;
    }
    __builtin_amdgcn_s_setprio(0);

    // causal mask only on the diagonal tile
    if (kt == qb) {
#pragma unroll
      for (int ct = 0; ct < 4; ct++)
#pragma unroll
        for (int j = 0; j < 4; j++) {
          int qr = qr0 + g * 4 + j;
          int kc = kv0 + ct * 16 + lr;
          if (kc > qr) s[ct][j] = -1e30f;
        }
    }

    // online softmax
    float pr[4][4];
    float sc[4];
#pragma unroll
    for (int j = 0; j < 4; j++) {
      float mx = fmaxf(fmaxf(s[0][j], s[1][j]), fmaxf(s[2][j], s[3][j]));
#pragma unroll
      for (int msk = 1; msk < 16; msk <<= 1) mx = fmaxf(mx, __shfl_xor(mx, msk));
      float mnew = fmaxf(mrow[j], mx);
      sc[j] = __expf(mrow[j] - mnew);
#pragma unroll
      for (int ct = 0; ct < 4; ct++) pr[ct][j] = __expf(s[ct][j] - mnew);
      float su = pr[0][j] + pr[1][j] + pr[2][j] + pr[3][j];
#pragma unroll
      for (int msk = 1; msk < 16; msk <<= 1) su += __shfl_xor(su, msk);
      lsum[j] = lsum[j] * sc[j] + su;
      mrow[j] = mnew;
    }
#pragma unroll
    for (int n = 0; n < 8; n++)
#pragma unroll
      for (int j = 0; j < 4; j++) acc[n][j] *= sc[j];

    // P -> LDS (per-wave private)
#pragma unroll
    for (int ct = 0; ct < 4; ct++)
#pragma unroll
      for (int j = 0; j < 4; j++)
        Plds[w][(g * 4 + j) * 72 + ct * 16 + lr] = f2bf(pr[ct][j]);

    // PV: acc += P[16x64] * V[64x128]
    short8 pa0 = *(const short8*)&Plds[w][lr * 72 + g * 8];
    short8 pa1 = *(const short8*)&Plds[w][lr * 72 + 32 + g * 8];
    __builtin_amdgcn_s_setprio(1);
#pragma unroll
    for (int n = 0; n < 8; n++) {
      int d = n * 16 + lr;
      short8 v0 = *(const short8*)&Vt[bi][d * 64 + ((g ^ (lr & 7)) << 3)];
      short8 v1 = *(const short8*)&Vt[bi][d * 64 + (((4 + g) ^ (lr & 7)) << 3)];
      acc[n] = __builtin_amdgcn_mfma_f32_16x16x32_bf16(pa0, v0, acc[n], 0, 0, 0);
      acc[n] = __builtin_amdgcn_mfma_f32_16x16x32_bf16(pa1, v1, acc[n], 0, 0, 0);
    }
    __builtin_amdgcn_s_setprio(0);
    __builtin_amdgcn_s_barrier();
  }
#undef STAGE

  // epilogue: O[t][h*128 + d]
#pragma unroll
  for (int n = 0; n < 8; n++)
#pragma unroll
    for (int j = 0; j < 4; j++) {
      int row = qr0 + g * 4 + j;
      int col = h * HD + n * 16 + lr;
      Ob[(size_t)row * HID + col] = f2bf(acc[n][j] / lsum[j]);
    }
}

// ---------- launcher ----------
extern "C" void kernel_launch(void* const* d_in, const int* in_sizes, int n_in,
                              void* d_out, int out_size, void* d_ws, size_t ws_size,
                              hipStream_t stream) {
  const float* x      = (const float*)d_in[0];
  const int*   pos    = (const int*)d_in[1];
  const float* w_qkv  = (const float*)d_in[2];
  const float* w_o    = (const float*)d_in[3];
  const float* qnw    = (const float*)d_in[4];
  const float* knw    = (const float*)d_in[5];
  float* out = (float*)d_out;

  char* ws = (char*)d_ws;
  const size_t MB = 1024 * 1024;
  unsigned short* x_bf   = (unsigned short*)(ws + 0);        // 8 MB  [2048][2048]
  unsigned short* Ob     = (unsigned short*)(ws + 0);        // reuses x_bf after GEMM1
  unsigned short* wqkv_t = (unsigned short*)(ws + 8 * MB);   // 16 MB [4096][2048]
  unsigned short* wo_t   = (unsigned short*)(ws + 24 * MB);  // 8 MB  [2048][2048]
  float*          qkv    = (float*)(ws + 32 * MB);           // 32 MB [2048][4096]
  unsigned short* Qb     = (unsigned short*)(ws + 64 * MB);  // 8 MB  [16][2048][128]
  unsigned short* Kb     = (unsigned short*)(ws + 72 * MB);  // 4 MB  [8][2048][128] (swizzled)
  unsigned short* Vtg    = (unsigned short*)(ws + 76 * MB);  // 4 MB  [8][32][128][64] (transposed+swizzled)

  k_cvt_bf16<<<(T_SEQ * HID) / 1024, 256, 0, stream>>>(x, x_bf);
  k_transpose_cvt<<<dim3(QKV_N / 32, HID / 32), dim3(32, 8), 0, stream>>>(w_qkv, wqkv_t, HID, QKV_N);
  k_transpose_cvt<<<dim3(HID / 32, HID / 32), dim3(32, 8), 0, stream>>>(w_o, wo_t, HID, HID);
  k_gemm_bt<<<dim3(QKV_N / 128, T_SEQ / 128), 256, 0, stream>>>(x_bf, wqkv_t, qkv, T_SEQ, QKV_N, HID);
  k_normrope<<<dim3(24, T_SEQ), 64, 0, stream>>>(qkv, pos, qnw, knw, Qb, Kb);
  k_vt<<<dim3(32, NKVH), 256, 0, stream>>>(qkv, Vtg);
  k_attn<<<512, 256, 0, stream>>>(Qb, Kb, Vtg, Ob);
  k_gemm_bt<<<dim3(HID / 128, T_SEQ / 128), 256, 0, stream>>>(Ob, wo_t, out, T_SEQ, HID, HID);
}

// Round 8
// 284.675 us; speedup vs baseline: 1.5290x; 1.0625x over previous
//
#include <hip/hip_runtime.h>
#include <hip/hip_bf16.h>
#include <stdint.h>

#define T_SEQ 2048
#define HID   2048
#define NQH   16
#define NKVH  8
#define HD    128
#define QKV_N 4096   // (16 + 2*8) * 128

typedef __attribute__((ext_vector_type(8))) short short8;
typedef __attribute__((ext_vector_type(4))) float f32x4;

// ---------- helpers ----------
__device__ inline unsigned short f2bf(float f) {
  union { float f; unsigned u; } v; v.f = f;
  unsigned r = (v.u + 0x7FFFu + ((v.u >> 16) & 1u)) >> 16;
  return (unsigned short)r;
}

__device__ inline unsigned int pack2bf(float lo, float hi) {
  return (unsigned int)f2bf(lo) | ((unsigned int)f2bf(hi) << 16);
}

__device__ inline void gld16(void* lds, const void* g) {
  __builtin_amdgcn_global_load_lds(
      (const __attribute__((address_space(1))) unsigned int*)g,
      (__attribute__((address_space(3))) unsigned int*)lds, 16, 0, 0);
}

// ---------- convert fp32 -> bf16 (elementwise, 4/thread) ----------
__global__ __launch_bounds__(256) void k_cvt_bf16(const float* __restrict__ in,
                                                  unsigned short* __restrict__ out) {
  int i = (blockIdx.x * 256 + threadIdx.x) * 4;
  float4 v = *(const float4*)&in[i];
  ushort4 o;
  o.x = f2bf(v.x); o.y = f2bf(v.y); o.z = f2bf(v.z); o.w = f2bf(v.w);
  *(ushort4*)&out[i] = o;
}

// ---------- transpose fp32 [R][C] -> bf16 [C][R] ----------
__global__ __launch_bounds__(256) void k_transpose_cvt(const float* __restrict__ in,
                                                       unsigned short* __restrict__ out,
                                                       int R, int C) {
  __shared__ float tile[32][33];
  int c0 = blockIdx.x * 32, r0 = blockIdx.y * 32;
  int tx = threadIdx.x, ty = threadIdx.y;
#pragma unroll
  for (int i = 0; i < 4; i++)
    tile[ty + 8 * i][tx] = in[(size_t)(r0 + ty + 8 * i) * C + c0 + tx];
  __syncthreads();
#pragma unroll
  for (int i = 0; i < 4; i++)
    out[(size_t)(c0 + ty + 8 * i) * R + r0 + tx] = f2bf(tile[tx][ty + 8 * i]);
}

// ---------- bf16 GEMM: C[M][N] = A[M][K] * Bt[N][K]^T  (m97 structure) ----------
__global__ __launch_bounds__(256) void k_gemm_bt(const unsigned short* __restrict__ A,
                                                 const unsigned short* __restrict__ Bt,
                                                 float* __restrict__ C,
                                                 int M, int N, int K) {
  __shared__ unsigned short Als[128 * 32];
  __shared__ unsigned short Bls[128 * 32];
  int tid = threadIdx.x;
  int w = tid >> 6, l = tid & 63;
  int bm = blockIdx.y, bn = blockIdx.x;
  int m0 = bm * 128, n0 = bn * 128;
  int wr = (w >> 1) * 64, wc = (w & 1) * 64;
  int lr = l & 15, g = l >> 4;

  f32x4 acc[4][4] = {};

  int eo0 = w * 1024 + l * 8;
  int sr0 = eo0 >> 5, sc0 = eo0 & 31;
  int eo1 = eo0 + 512;
  int sr1 = eo1 >> 5, sc1 = eo1 & 31;

  int NT = K / 32;
  for (int t = 0; t < NT; t++) {
    int k0 = t * 32;
    gld16(&Als[w * 1024],       &A[(size_t)(m0 + sr0) * K + k0 + sc0]);
    gld16(&Als[w * 1024 + 512], &A[(size_t)(m0 + sr1) * K + k0 + sc1]);
    gld16(&Bls[w * 1024],       &Bt[(size_t)(n0 + sr0) * K + k0 + sc0]);
    gld16(&Bls[w * 1024 + 512], &Bt[(size_t)(n0 + sr1) * K + k0 + sc1]);
    __syncthreads();
    short8 af[4], bfr[4];
#pragma unroll
    for (int m = 0; m < 4; m++) af[m]  = *(const short8*)&Als[(wr + m * 16 + lr) * 32 + g * 8];
#pragma unroll
    for (int n = 0; n < 4; n++) bfr[n] = *(const short8*)&Bls[(wc + n * 16 + lr) * 32 + g * 8];
#pragma unroll
    for (int m = 0; m < 4; m++)
#pragma unroll
      for (int n = 0; n < 4; n++)
        acc[m][n] = __builtin_amdgcn_mfma_f32_16x16x32_bf16(af[m], bfr[n], acc[m][n], 0, 0, 0);
    __syncthreads();
  }

#pragma unroll
  for (int m = 0; m < 4; m++)
#pragma unroll
    for (int n = 0; n < 4; n++)
#pragma unroll
      for (int j = 0; j < 4; j++) {
        int row = m0 + wr + m * 16 + g * 4 + j;
        int col = n0 + wc + n * 16 + lr;
        C[(size_t)row * N + col] = acc[m][n][j];
      }
}

// ---------- fused per-head RMSNorm + RoPE (Q and K heads only) ----------
// K is stored with the per-row XOR swizzle d' = d ^ ((t&7)<<3) so that the
// attention kernel can global_load_lds it linearly and read MFMA fragments
// conflict-free. (Permutes 16B blocks within each 256B row: coalescing intact.)
__global__ __launch_bounds__(64) void k_normrope(const float* __restrict__ qkv,
                                                 const int* __restrict__ pos_ids,
                                                 const float* __restrict__ qw,
                                                 const float* __restrict__ kw,
                                                 unsigned short* __restrict__ Qb,
                                                 unsigned short* __restrict__ Kb) {
  int slot = blockIdx.x;  // 0..15 q heads, 16..23 k heads
  int t = blockIdx.y;
  int l = threadIdx.x;    // 0..63
  const float* src = &qkv[(size_t)t * QKV_N + slot * HD];
  float a = src[l], b = src[l + 64];

  float ss = a * a + b * b;
#pragma unroll
  for (int m = 1; m < 64; m <<= 1) ss += __shfl_xor(ss, m);
  float r = rsqrtf(ss * (1.0f / 128.0f) + 1e-6f);
  const float* nw = (slot < 16) ? qw : kw;
  a *= r * nw[l];
  b *= r * nw[l + 64];
  float p = (float)pos_ids[t];
  float invf = exp2f(-(float)l * 0.31143075889569023f);  // log2(1e6)/64
  float ang = p * invf;
  float cs = cosf(ang), sn = sinf(ang);
  float oa = a * cs - b * sn;
  float ob = b * cs + a * sn;
  if (slot < 16) {
    const float s = 0.08838834764831845f;  // 1/sqrt(128), fold attn scale into Q
    oa *= s; ob *= s;
    size_t d = ((size_t)slot * T_SEQ + t) * HD;
    Qb[d + l] = f2bf(oa); Qb[d + 64 + l] = f2bf(ob);
  } else {
    size_t d = ((size_t)(slot - 16) * T_SEQ + t) * HD;
    int sw = (t & 7) << 3;
    Kb[d + (l ^ sw)] = f2bf(oa); Kb[d + ((l + 64) ^ sw)] = f2bf(ob);
  }
}

// ---------- V: cvt + transpose + swizzle straight from the fp32 qkv buffer ----------
// Output layout: Vtg[kvh][blk][d][kv'] , kv' block-index = (kv>>3) ^ (d&7),
// i.e. the exact LDS image attention wants, so staging is a linear gld16 copy.
__global__ __launch_bounds__(256) void k_vt(const float* __restrict__ qkv,
                                            unsigned short* __restrict__ Vtg) {
  __shared__ unsigned short t[64 * 136];
  int kvh = blockIdx.y, blk = blockIdx.x;
  int tid = threadIdx.x;
  const float* src = &qkv[(size_t)(blk * 64) * QKV_N + (24 + kvh) * HD];
#pragma unroll
  for (int r = 0; r < 8; r++) {     // 2048 chunks of 4 floats = full 64x128 tile
    int c = tid + r * 256;
    int row = c >> 5, col = (c & 31) * 4;
    float4 v = *(const float4*)&src[(size_t)row * QKV_N + col];
    ushort4 o;
    o.x = f2bf(v.x); o.y = f2bf(v.y); o.z = f2bf(v.z); o.w = f2bf(v.w);
    *(ushort4*)&t[row * 136 + col] = o;
  }
  __syncthreads();
  unsigned short* dst = &Vtg[((size_t)kvh * 32 + blk) * 8192];
#pragma unroll
  for (int r = 0; r < 4; r++) {
    int c = tid + r * 256;           // 1024 chunks of 8 kv
    int d = c >> 3, kb = c & 7;
    short8 v;
#pragma unroll
    for (int i = 0; i < 8; i++) v[i] = t[(kb * 8 + i) * 136 + d];
    *(short8*)&dst[d * 64 + ((kb ^ (d & 7)) << 3)] = v;
  }
}

// ---------- causal GQA flash attention, v4: swapped QK^T, in-lane softmax ----------
// 512 blocks: qb = 31 - bid>>4 (heavy first), h = bid&15. 4 waves x 16 q-rows.
// QK^T computed as mfma(K, Q) so lane (lr,g) holds S[k=ct*16+g*4+j][q=lr]:
// softmax row-reduce = in-register tree + 2 shfl_xor (g-groups), no per-row chains.
// P repacked to PV A-fragments via wave-private LDS (stride-36 dwords: b128-aligned,
// conflict-free read). Per-q-row scale/lsum broadcast to acc lanes via 4 shfl.
__global__ __launch_bounds__(256, 2) void k_attn(const unsigned short* __restrict__ Qb,
                                                 const unsigned short* __restrict__ Kb,
                                                 const unsigned short* __restrict__ Vtg,
                                                 unsigned short* __restrict__ Ob) {
  __shared__ unsigned short Klds[2][64 * 128];
  __shared__ unsigned short Vt[2][64 * 128];
  __shared__ unsigned int Pld[4][16 * 36];   // per-wave P, [q-row][36 dwords]

  int bid = blockIdx.x;
  int qb = 31 - (bid >> 4);
  int h = bid & 15, kvh = h >> 1;
  int tid = threadIdx.x, w = tid >> 6, l = tid & 63;
  int lr = l & 15, g = l >> 4;
  int qr0 = qb * 64 + w * 16;

  // Q fragments, attn scale folded in
  short8 qf[4];
  const unsigned short* qrow = &Qb[((size_t)h * T_SEQ + qr0 + lr) * HD];
#pragma unroll
  for (int c = 0; c < 4; c++) qf[c] = *(const short8*)&qrow[c * 32 + g * 8];

  f32x4 acc[8] = {};
  float mrow = -1e30f, lsum = 0.0f;  // per-lane state for q-row (qr0 + lr)

  const unsigned short* Ksrc = &Kb[(size_t)kvh * T_SEQ * HD];
  const unsigned short* Vsrc = &Vtg[(size_t)kvh * 32 * 8192];

#define STAGE(bi, kt) do {                                          \
    const unsigned short* ks_ = Ksrc + (size_t)(kt) * 8192;         \
    const unsigned short* vs_ = Vsrc + (size_t)(kt) * 8192;         \
    _Pragma("unroll")                                               \
    for (int r_ = 0; r_ < 4; r_++) {                                \
      int cb_ = r_ * 256 + w * 64;                                  \
      gld16(&Klds[bi][cb_ * 8], ks_ + (size_t)(cb_ + l) * 8);       \
      gld16(&Vt[bi][cb_ * 8],   vs_ + (size_t)(cb_ + l) * 8);       \
    }                                                               \
  } while (0)

  int NT = qb + 1;
  STAGE(0, 0);
  for (int kt = 0; kt < NT; kt++) {
    int bi = kt & 1;
    if (kt + 1 < NT) {
      STAGE(bi ^ 1, kt + 1);
      asm volatile("s_waitcnt vmcnt(8)" ::: "memory");
    } else {
      asm volatile("s_waitcnt vmcnt(0)" ::: "memory");
    }
    __builtin_amdgcn_s_barrier();
    __builtin_amdgcn_sched_barrier(0);

    int kv0 = kt * 64;
    // S^T = K Q^T : s[ct][j] = S[k = kv0+ct*16+g*4+j][q = qr0+lr]
    f32x4 s[4];
    __builtin_amdgcn_s_setprio(1);
#pragma unroll
    for (int ct = 0; ct < 4; ct++) {
      f32x4 sv = {};
#pragma unroll
      for (int dc = 0; dc < 4; dc++) {
        int dsw = (dc * 32 + g * 8) ^ ((lr & 7) << 3);
        short8 kf = *(const short8*)&Klds[bi][(ct * 16 + lr) * 128 + dsw];
        sv = __builtin_amdgcn_mfma_f32_16x16x32_bf16(kf, qf[dc], sv, 0, 0, 0);
      }
      s[ct] = sv;
    }
    __builtin_amdgcn_s_setprio(0);

    // causal mask only on the diagonal tile: k > q
    if (kt == qb) {
#pragma unroll
      for (int ct = 0; ct < 4; ct++)
#pragma unroll
        for (int j = 0; j < 4; j++) {
          int kc = kv0 + ct * 16 + g * 4 + j;
          if (kc > qr0 + lr) s[ct][j] = -1e30f;
        }
    }

    // in-lane row max over 16 values, then combine g-groups (2 shfl)
    float mx0 = fmaxf(fmaxf(s[0][0], s[0][1]), fmaxf(s[0][2], s[0][3]));
    float mx1 = fmaxf(fmaxf(s[1][0], s[1][1]), fmaxf(s[1][2], s[1][3]));
    float mx2 = fmaxf(fmaxf(s[2][0], s[2][1]), fmaxf(s[2][2], s[2][3]));
    float mx3 = fmaxf(fmaxf(s[3][0], s[3][1]), fmaxf(s[3][2], s[3][3]));
    float mx = fmaxf(fmaxf(mx0, mx1), fmaxf(mx2, mx3));
    mx = fmaxf(mx, __shfl_xor(mx, 16));
    mx = fmaxf(mx, __shfl_xor(mx, 32));

    float mnew = fmaxf(mrow, mx);
    float scale = __expf(mrow - mnew);
    mrow = mnew;

    float p[4][4];
#pragma unroll
    for (int ct = 0; ct < 4; ct++)
#pragma unroll
      for (int j = 0; j < 4; j++) p[ct][j] = __expf(s[ct][j] - mnew);

    float su0 = (p[0][0] + p[0][1]) + (p[0][2] + p[0][3]);
    float su1 = (p[1][0] + p[1][1]) + (p[1][2] + p[1][3]);
    float su2 = (p[2][0] + p[2][1]) + (p[2][2] + p[2][3]);
    float su3 = (p[3][0] + p[3][1]) + (p[3][2] + p[3][3]);
    float su = (su0 + su1) + (su2 + su3);
    su += __shfl_xor(su, 16);
    su += __shfl_xor(su, 32);
    lsum = lsum * scale + su;

    // broadcast per-q-row rescale to accumulator lanes (acc q-row = g*4+j)
    float scj[4];
#pragma unroll
    for (int j = 0; j < 4; j++) scj[j] = __shfl(scale, g * 4 + j);
#pragma unroll
    for (int n = 0; n < 8; n++)
#pragma unroll
      for (int j = 0; j < 4; j++) acc[n][j] *= scj[j];

    // pack P -> wave-private LDS: row q=lr, dword idx = k/2 (stride 36)
    unsigned int* pw = &Pld[w][lr * 36];
#pragma unroll
    for (int ct = 0; ct < 4; ct++) {
      pw[ct * 8 + g * 2 + 0] = pack2bf(p[ct][0], p[ct][1]);
      pw[ct * 8 + g * 2 + 1] = pack2bf(p[ct][2], p[ct][3]);
    }

    // read PV A-fragments: lane (lr,g) needs P[q=lr][k = ks*32 + g*8 .. +7]
    short8 pa0 = *(const short8*)&Pld[w][lr * 36 + g * 4];
    short8 pa1 = *(const short8*)&Pld[w][lr * 36 + 16 + g * 4];

    // PV: acc += P[16x64] * V[64x128]
    __builtin_amdgcn_s_setprio(1);
#pragma unroll
    for (int n = 0; n < 8; n++) {
      int d = n * 16 + lr;
      short8 v0 = *(const short8*)&Vt[bi][d * 64 + ((g ^ (lr & 7)) << 3)];
      short8 v1 = *(const short8*)&Vt[bi][d * 64 + (((4 + g) ^ (lr & 7)) << 3)];
      acc[n] = __builtin_amdgcn_mfma_f32_16x16x32_bf16(pa0, v0, acc[n], 0, 0, 0);
      acc[n] = __builtin_amdgcn_mfma_f32_16x16x32_bf16(pa1, v1, acc[n], 0, 0, 0);
    }
    __builtin_amdgcn_s_setprio(0);
    __builtin_amdgcn_s_barrier();
  }
#undef STAGE

  // epilogue: per-q-row 1/lsum broadcast, O[t][h*128 + d]
  float linv = 1.0f / lsum;
  float lj[4];
#pragma unroll
  for (int j = 0; j < 4; j++) lj[j] = __shfl(linv, g * 4 + j);
#pragma unroll
  for (int n = 0; n < 8; n++)
#pragma unroll
    for (int j = 0; j < 4; j++) {
      int row = qr0 + g * 4 + j;
      int col = h * HD + n * 16 + lr;
      Ob[(size_t)row * HID + col] = f2bf(acc[n][j] * lj[j]);
    }
}

// ---------- launcher ----------
extern "C" void kernel_launch(void* const* d_in, const int* in_sizes, int n_in,
                              void* d_out, int out_size, void* d_ws, size_t ws_size,
                              hipStream_t stream) {
  const float* x      = (const float*)d_in[0];
  const int*   pos    = (const int*)d_in[1];
  const float* w_qkv  = (const float*)d_in[2];
  const float* w_o    = (const float*)d_in[3];
  const float* qnw    = (const float*)d_in[4];
  const float* knw    = (const float*)d_in[5];
  float* out = (float*)d_out;

  char* ws = (char*)d_ws;
  const size_t MB = 1024 * 1024;
  unsigned short* x_bf   = (unsigned short*)(ws + 0);        // 8 MB  [2048][2048]
  unsigned short* Ob     = (unsigned short*)(ws + 0);        // reuses x_bf after GEMM1
  unsigned short* wqkv_t = (unsigned short*)(ws + 8 * MB);   // 16 MB [4096][2048]
  unsigned short* wo_t   = (unsigned short*)(ws + 24 * MB);  // 8 MB  [2048][2048]
  float*          qkv    = (float*)(ws + 32 * MB);           // 32 MB [2048][4096]
  unsigned short* Qb     = (unsigned short*)(ws + 64 * MB);  // 8 MB  [16][2048][128]
  unsigned short* Kb     = (unsigned short*)(ws + 72 * MB);  // 4 MB  [8][2048][128] (swizzled)
  unsigned short* Vtg    = (unsigned short*)(ws + 76 * MB);  // 4 MB  [8][32][128][64] (transposed+swizzled)

  k_cvt_bf16<<<(T_SEQ * HID) / 1024, 256, 0, stream>>>(x, x_bf);
  k_transpose_cvt<<<dim3(QKV_N / 32, HID / 32), dim3(32, 8), 0, stream>>>(w_qkv, wqkv_t, HID, QKV_N);
  k_transpose_cvt<<<dim3(HID / 32, HID / 32), dim3(32, 8), 0, stream>>>(w_o, wo_t, HID, HID);
  k_gemm_bt<<<dim3(QKV_N / 128, T_SEQ / 128), 256, 0, stream>>>(x_bf, wqkv_t, qkv, T_SEQ, QKV_N, HID);
  k_normrope<<<dim3(24, T_SEQ), 64, 0, stream>>>(qkv, pos, qnw, knw, Qb, Kb);
  k_vt<<<dim3(32, NKVH), 256, 0, stream>>>(qkv, Vtg);
  k_attn<<<512, 256, 0, stream>>>(Qb, Kb, Vtg, Ob);
  k_gemm_bt<<<dim3(HID / 128, T_SEQ / 128), 256, 0, stream>>>(Ob, wo_t, out, T_SEQ, HID, HID);
}

// Round 9
// 278.608 us; speedup vs baseline: 1.5623x; 1.0218x over previous
//
#include <hip/hip_runtime.h>
#include <hip/hip_bf16.h>
#include <stdint.h>

#define T_SEQ 2048
#define HID   2048
#define NQH   16
#define NKVH  8
#define HD    128
#define QKV_N 4096   // (16 + 2*8) * 128

typedef __attribute__((ext_vector_type(8))) short short8;
typedef __attribute__((ext_vector_type(4))) float f32x4;

// ---------- helpers ----------
__device__ inline unsigned short f2bf(float f) {
  union { float f; unsigned u; } v; v.f = f;
  unsigned r = (v.u + 0x7FFFu + ((v.u >> 16) & 1u)) >> 16;
  return (unsigned short)r;
}

__device__ inline unsigned int pack2bf(float lo, float hi) {
  return (unsigned int)f2bf(lo) | ((unsigned int)f2bf(hi) << 16);
}

__device__ inline void gld16(void* lds, const void* g) {
  __builtin_amdgcn_global_load_lds(
      (const __attribute__((address_space(1))) unsigned int*)g,
      (__attribute__((address_space(3))) unsigned int*)lds, 16, 0, 0);
}

// ---------- convert fp32 -> bf16 (elementwise, 4/thread) ----------
__global__ __launch_bounds__(256) void k_cvt_bf16(const float* __restrict__ in,
                                                  unsigned short* __restrict__ out) {
  int i = (blockIdx.x * 256 + threadIdx.x) * 4;
  float4 v = *(const float4*)&in[i];
  ushort4 o;
  o.x = f2bf(v.x); o.y = f2bf(v.y); o.z = f2bf(v.z); o.w = f2bf(v.w);
  *(ushort4*)&out[i] = o;
}

// ---------- transpose fp32 [R][C] -> bf16 [C][R] ----------
__global__ __launch_bounds__(256) void k_transpose_cvt(const float* __restrict__ in,
                                                       unsigned short* __restrict__ out,
                                                       int R, int C) {
  __shared__ float tile[32][33];
  int c0 = blockIdx.x * 32, r0 = blockIdx.y * 32;
  int tx = threadIdx.x, ty = threadIdx.y;
#pragma unroll
  for (int i = 0; i < 4; i++)
    tile[ty + 8 * i][tx] = in[(size_t)(r0 + ty + 8 * i) * C + c0 + tx];
  __syncthreads();
#pragma unroll
  for (int i = 0; i < 4; i++)
    out[(size_t)(c0 + ty + 8 * i) * R + r0 + tx] = f2bf(tile[tx][ty + 8 * i]);
}

// ---------- bf16 GEMM, 8-phase counted-vmcnt (T2+T3+T4+T5) ----------
// C[M][N] = A[M][K] * Bt[N][K]^T. BM=128 BN=256 BK=64, 8 waves (2Mx4N),
// wave tile 64x64, double-buffered LDS (96KB). LDS layout: [row][64] with
// 16B-block XOR swizzle blk' = blk ^ (row&7), applied on the global SOURCE
// address at global_load_lds (linear LDS dest) and on the ds_read address.
// Per K-tile: A staged pre-phase + vmcnt(2) counted gate; B staged in ph0/ph1;
// 4 phases each {ds_read ; stage ; barrier ; lgkmcnt(0) ; 8 MFMA ; barrier}.
__global__ __launch_bounds__(512, 1) void k_gemm8(const unsigned short* __restrict__ A,
                                                  const unsigned short* __restrict__ Bt,
                                                  float* __restrict__ C,
                                                  int M, int N, int K) {
  __shared__ unsigned short Als[2][128 * 64];
  __shared__ unsigned short Bls[2][256 * 64];
  int tid = threadIdx.x;
  int w = tid >> 6, l = tid & 63;
  int lr = l & 15, g = l >> 4;
  int m0 = blockIdx.y * 128, n0 = blockIdx.x * 256;
  int rA = (w >> 2) * 64;   // wave row base in A tile
  int rB = (w & 3) * 64;    // wave row base in B tile

  f32x4 acc[4][4] = {};

// stage one 512-slot round (16B/slot); slot s = r_*512 + w*64 + l;
// LDS dest linear, global source block-swizzled (inverse of read swizzle).
#define STG_A(bi, kt, r_) do {                                              \
    int sb_ = (r_) * 512 + w * 64;                                          \
    int s_ = sb_ + l, rr_ = s_ >> 3, cc_ = s_ & 7;                          \
    gld16(&Als[bi][sb_ * 8],                                                \
          A + (size_t)(m0 + rr_) * K + (kt) * 64 + ((cc_ ^ (rr_ & 7)) << 3)); \
  } while (0)
#define STG_B(bi, kt, r_) do {                                              \
    int sb_ = (r_) * 512 + w * 64;                                          \
    int s_ = sb_ + l, rr_ = s_ >> 3, cc_ = s_ & 7;                          \
    gld16(&Bls[bi][sb_ * 8],                                                \
          Bt + (size_t)(n0 + rr_) * K + (kt) * 64 + ((cc_ ^ (rr_ & 7)) << 3)); \
  } while (0)
// swizzled fragment reads: row, k-block kk*4+g (kk = krep)
#define RD_A(bi, q, kk) (*(const short8*)&Als[bi][(rA + (q) * 16 + lr) * 64 + ((((kk) * 4 + g) ^ (lr & 7)) << 3)])
#define RD_B(bi, n, kk) (*(const short8*)&Bls[bi][(rB + (n) * 16 + lr) * 64 + ((((kk) * 4 + g) ^ (lr & 7)) << 3)])

  // prologue: stage K-tile 0 into buffer 0 (6 rounds)
  STG_A(0, 0, 0); STG_A(0, 0, 1);
  STG_B(0, 0, 0); STG_B(0, 0, 1); STG_B(0, 0, 2); STG_B(0, 0, 3);

  int NT = K / 64;
  for (int t = 0; t < NT; t++) {
    int cur = t & 1, nxt = cur ^ 1;
    bool pre = (t + 1 < NT);
    if (pre) {
      STG_A(nxt, t + 1, 0); STG_A(nxt, t + 1, 1);
      asm volatile("s_waitcnt vmcnt(2)" ::: "memory");  // cur's 6 landed; 2 fly
    } else {
      asm volatile("s_waitcnt vmcnt(0)" ::: "memory");
    }
    __builtin_amdgcn_s_barrier();

    // ph0: all B frags (8) + A row-quadrant 0 (2); stage B rounds 0,1
    short8 bfr[2][4];
#pragma unroll
    for (int kk = 0; kk < 2; kk++)
#pragma unroll
      for (int n = 0; n < 4; n++) bfr[kk][n] = RD_B(cur, n, kk);
    short8 a0 = RD_A(cur, 0, 0), a1 = RD_A(cur, 0, 1);
    if (pre) { STG_B(nxt, t + 1, 0); STG_B(nxt, t + 1, 1); }
    __builtin_amdgcn_s_barrier();
    asm volatile("s_waitcnt lgkmcnt(0)" ::: "memory");
    __builtin_amdgcn_sched_barrier(0);
    __builtin_amdgcn_s_setprio(1);
#pragma unroll
    for (int n = 0; n < 4; n++) {
      acc[0][n] = __builtin_amdgcn_mfma_f32_16x16x32_bf16(a0, bfr[0][n], acc[0][n], 0, 0, 0);
      acc[0][n] = __builtin_amdgcn_mfma_f32_16x16x32_bf16(a1, bfr[1][n], acc[0][n], 0, 0, 0);
    }
    __builtin_amdgcn_s_setprio(0);
    __builtin_amdgcn_s_barrier();

    // ph1..ph3: A row-quadrants 1..3; ph1 stages B rounds 2,3
#pragma unroll
    for (int q = 1; q < 4; q++) {
      short8 ak0 = RD_A(cur, q, 0), ak1 = RD_A(cur, q, 1);
      if (q == 1 && pre) { STG_B(nxt, t + 1, 2); STG_B(nxt, t + 1, 3); }
      __builtin_amdgcn_s_barrier();
      asm volatile("s_waitcnt lgkmcnt(0)" ::: "memory");
      __builtin_amdgcn_sched_barrier(0);
      __builtin_amdgcn_s_setprio(1);
#pragma unroll
      for (int n = 0; n < 4; n++) {
        acc[q][n] = __builtin_amdgcn_mfma_f32_16x16x32_bf16(ak0, bfr[0][n], acc[q][n], 0, 0, 0);
        acc[q][n] = __builtin_amdgcn_mfma_f32_16x16x32_bf16(ak1, bfr[1][n], acc[q][n], 0, 0, 0);
      }
      __builtin_amdgcn_s_setprio(0);
      __builtin_amdgcn_s_barrier();
    }
  }
#undef STG_A
#undef STG_B
#undef RD_A
#undef RD_B

#pragma unroll
  for (int mq = 0; mq < 4; mq++)
#pragma unroll
    for (int n = 0; n < 4; n++)
#pragma unroll
      for (int j = 0; j < 4; j++) {
        int row = m0 + rA + mq * 16 + g * 4 + j;
        int col = n0 + rB + n * 16 + lr;
        C[(size_t)row * N + col] = acc[mq][n][j];
      }
}

// ---------- fused per-head RMSNorm + RoPE (Q and K heads only) ----------
// K is stored with the per-row XOR swizzle d' = d ^ ((t&7)<<3) so that the
// attention kernel can global_load_lds it linearly and read MFMA fragments
// conflict-free. (Permutes 16B blocks within each 256B row: coalescing intact.)
__global__ __launch_bounds__(64) void k_normrope(const float* __restrict__ qkv,
                                                 const int* __restrict__ pos_ids,
                                                 const float* __restrict__ qw,
                                                 const float* __restrict__ kw,
                                                 unsigned short* __restrict__ Qb,
                                                 unsigned short* __restrict__ Kb) {
  int slot = blockIdx.x;  // 0..15 q heads, 16..23 k heads
  int t = blockIdx.y;
  int l = threadIdx.x;    // 0..63
  const float* src = &qkv[(size_t)t * QKV_N + slot * HD];
  float a = src[l], b = src[l + 64];

  float ss = a * a + b * b;
#pragma unroll
  for (int m = 1; m < 64; m <<= 1) ss += __shfl_xor(ss, m);
  float r = rsqrtf(ss * (1.0f / 128.0f) + 1e-6f);
  const float* nw = (slot < 16) ? qw : kw;
  a *= r * nw[l];
  b *= r * nw[l + 64];
  float p = (float)pos_ids[t];
  float invf = exp2f(-(float)l * 0.31143075889569023f);  // log2(1e6)/64
  float ang = p * invf;
  float cs = cosf(ang), sn = sinf(ang);
  float oa = a * cs - b * sn;
  float ob = b * cs + a * sn;
  if (slot < 16) {
    const float s = 0.08838834764831845f;  // 1/sqrt(128), fold attn scale into Q
    oa *= s; ob *= s;
    size_t d = ((size_t)slot * T_SEQ + t) * HD;
    Qb[d + l] = f2bf(oa); Qb[d + 64 + l] = f2bf(ob);
  } else {
    size_t d = ((size_t)(slot - 16) * T_SEQ + t) * HD;
    int sw = (t & 7) << 3;
    Kb[d + (l ^ sw)] = f2bf(oa); Kb[d + ((l + 64) ^ sw)] = f2bf(ob);
  }
}

// ---------- V: cvt + transpose + swizzle straight from the fp32 qkv buffer ----------
// Output layout: Vtg[kvh][blk][d][kv'] , kv' block-index = (kv>>3) ^ (d&7),
// i.e. the exact LDS image attention wants, so staging is a linear gld16 copy.
__global__ __launch_bounds__(256) void k_vt(const float* __restrict__ qkv,
                                            unsigned short* __restrict__ Vtg) {
  __shared__ unsigned short t[64 * 136];
  int kvh = blockIdx.y, blk = blockIdx.x;
  int tid = threadIdx.x;
  const float* src = &qkv[(size_t)(blk * 64) * QKV_N + (24 + kvh) * HD];
#pragma unroll
  for (int r = 0; r < 8; r++) {     // 2048 chunks of 4 floats = full 64x128 tile
    int c = tid + r * 256;
    int row = c >> 5, col = (c & 31) * 4;
    float4 v = *(const float4*)&src[(size_t)row * QKV_N + col];
    ushort4 o;
    o.x = f2bf(v.x); o.y = f2bf(v.y); o.z = f2bf(v.z); o.w = f2bf(v.w);
    *(ushort4*)&t[row * 136 + col] = o;
  }
  __syncthreads();
  unsigned short* dst = &Vtg[((size_t)kvh * 32 + blk) * 8192];
#pragma unroll
  for (int r = 0; r < 4; r++) {
    int c = tid + r * 256;           // 1024 chunks of 8 kv
    int d = c >> 3, kb = c & 7;
    short8 v;
#pragma unroll
    for (int i = 0; i < 8; i++) v[i] = t[(kb * 8 + i) * 136 + d];
    *(short8*)&dst[d * 64 + ((kb ^ (d & 7)) << 3)] = v;
  }
}

// ---------- causal GQA flash attention, v4: swapped QK^T, in-lane softmax ----------
__global__ __launch_bounds__(256, 2) void k_attn(const unsigned short* __restrict__ Qb,
                                                 const unsigned short* __restrict__ Kb,
                                                 const unsigned short* __restrict__ Vtg,
                                                 unsigned short* __restrict__ Ob) {
  __shared__ unsigned short Klds[2][64 * 128];
  __shared__ unsigned short Vt[2][64 * 128];
  __shared__ unsigned int Pld[4][16 * 36];   // per-wave P, [q-row][36 dwords]

  int bid = blockIdx.x;
  int qb = 31 - (bid >> 4);
  int h = bid & 15, kvh = h >> 1;
  int tid = threadIdx.x, w = tid >> 6, l = tid & 63;
  int lr = l & 15, g = l >> 4;
  int qr0 = qb * 64 + w * 16;

  short8 qf[4];
  const unsigned short* qrow = &Qb[((size_t)h * T_SEQ + qr0 + lr) * HD];
#pragma unroll
  for (int c = 0; c < 4; c++) qf[c] = *(const short8*)&qrow[c * 32 + g * 8];

  f32x4 acc[8] = {};
  float mrow = -1e30f, lsum = 0.0f;

  const unsigned short* Ksrc = &Kb[(size_t)kvh * T_SEQ * HD];
  const unsigned short* Vsrc = &Vtg[(size_t)kvh * 32 * 8192];

#define STAGE(bi, kt) do {                                          \
    const unsigned short* ks_ = Ksrc + (size_t)(kt) * 8192;         \
    const unsigned short* vs_ = Vsrc + (size_t)(kt) * 8192;         \
    _Pragma("unroll")                                               \
    for (int r_ = 0; r_ < 4; r_++) {                                \
      int cb_ = r_ * 256 + w * 64;                                  \
      gld16(&Klds[bi][cb_ * 8], ks_ + (size_t)(cb_ + l) * 8);       \
      gld16(&Vt[bi][cb_ * 8],   vs_ + (size_t)(cb_ + l) * 8);       \
    }                                                               \
  } while (0)

  int NT = qb + 1;
  STAGE(0, 0);
  for (int kt = 0; kt < NT; kt++) {
    int bi = kt & 1;
    if (kt + 1 < NT) {
      STAGE(bi ^ 1, kt + 1);
      asm volatile("s_waitcnt vmcnt(8)" ::: "memory");
    } else {
      asm volatile("s_waitcnt vmcnt(0)" ::: "memory");
    }
    __builtin_amdgcn_s_barrier();
    __builtin_amdgcn_sched_barrier(0);

    int kv0 = kt * 64;
    f32x4 s[4];
    __builtin_amdgcn_s_setprio(1);
#pragma unroll
    for (int ct = 0; ct < 4; ct++) {
      f32x4 sv = {};
#pragma unroll
      for (int dc = 0; dc < 4; dc++) {
        int dsw = (dc * 32 + g * 8) ^ ((lr & 7) << 3);
        short8 kf = *(const short8*)&Klds[bi][(ct * 16 + lr) * 128 + dsw];
        sv = __builtin_amdgcn_mfma_f32_16x16x32_bf16(kf, qf[dc], sv, 0, 0, 0);
      }
      s[ct] = sv;
    }
    __builtin_amdgcn_s_setprio(0);

    if (kt == qb) {
#pragma unroll
      for (int ct = 0; ct < 4; ct++)
#pragma unroll
        for (int j = 0; j < 4; j++) {
          int kc = kv0 + ct * 16 + g * 4 + j;
          if (kc > qr0 + lr) s[ct][j] = -1e30f;
        }
    }

    float mx0 = fmaxf(fmaxf(s[0][0], s[0][1]), fmaxf(s[0][2], s[0][3]));
    float mx1 = fmaxf(fmaxf(s[1][0], s[1][1]), fmaxf(s[1][2], s[1][3]));
    float mx2 = fmaxf(fmaxf(s[2][0], s[2][1]), fmaxf(s[2][2], s[2][3]));
    float mx3 = fmaxf(fmaxf(s[3][0], s[3][1]), fmaxf(s[3][2], s[3][3]));
    float mx = fmaxf(fmaxf(mx0, mx1), fmaxf(mx2, mx3));
    mx = fmaxf(mx, __shfl_xor(mx, 16));
    mx = fmaxf(mx, __shfl_xor(mx, 32));

    float mnew = fmaxf(mrow, mx);
    float scale = __expf(mrow - mnew);
    mrow = mnew;

    float p[4][4];
#pragma unroll
    for (int ct = 0; ct < 4; ct++)
#pragma unroll
      for (int j = 0; j < 4; j++) p[ct][j] = __expf(s[ct][j] - mnew);

    float su0 = (p[0][0] + p[0][1]) + (p[0][2] + p[0][3]);
    float su1 = (p[1][0] + p[1][1]) + (p[1][2] + p[1][3]);
    float su2 = (p[2][0] + p[2][1]) + (p[2][2] + p[2][3]);
    float su3 = (p[3][0] + p[3][1]) + (p[3][2] + p[3][3]);
    float su = (su0 + su1) + (su2 + su3);
    su += __shfl_xor(su, 16);
    su += __shfl_xor(su, 32);
    lsum = lsum * scale + su;

    float scj[4];
#pragma unroll
    for (int j = 0; j < 4; j++) scj[j] = __shfl(scale, g * 4 + j);
#pragma unroll
    for (int n = 0; n < 8; n++)
#pragma unroll
      for (int j = 0; j < 4; j++) acc[n][j] *= scj[j];

    unsigned int* pw = &Pld[w][lr * 36];
#pragma unroll
    for (int ct = 0; ct < 4; ct++) {
      pw[ct * 8 + g * 2 + 0] = pack2bf(p[ct][0], p[ct][1]);
      pw[ct * 8 + g * 2 + 1] = pack2bf(p[ct][2], p[ct][3]);
    }

    short8 pa0 = *(const short8*)&Pld[w][lr * 36 + g * 4];
    short8 pa1 = *(const short8*)&Pld[w][lr * 36 + 16 + g * 4];

    __builtin_amdgcn_s_setprio(1);
#pragma unroll
    for (int n = 0; n < 8; n++) {
      int d = n * 16 + lr;
      short8 v0 = *(const short8*)&Vt[bi][d * 64 + ((g ^ (lr & 7)) << 3)];
      short8 v1 = *(const short8*)&Vt[bi][d * 64 + (((4 + g) ^ (lr & 7)) << 3)];
      acc[n] = __builtin_amdgcn_mfma_f32_16x16x32_bf16(pa0, v0, acc[n], 0, 0, 0);
      acc[n] = __builtin_amdgcn_mfma_f32_16x16x32_bf16(pa1, v1, acc[n], 0, 0, 0);
    }
    __builtin_amdgcn_s_setprio(0);
    __builtin_amdgcn_s_barrier();
  }
#undef STAGE

  float linv = 1.0f / lsum;
  float lj[4];
#pragma unroll
  for (int j = 0; j < 4; j++) lj[j] = __shfl(linv, g * 4 + j);
#pragma unroll
  for (int n = 0; n < 8; n++)
#pragma unroll
    for (int j = 0; j < 4; j++) {
      int row = qr0 + g * 4 + j;
      int col = h * HD + n * 16 + lr;
      Ob[(size_t)row * HID + col] = f2bf(acc[n][j] * lj[j]);
    }
}

// ---------- launcher ----------
extern "C" void kernel_launch(void* const* d_in, const int* in_sizes, int n_in,
                              void* d_out, int out_size, void* d_ws, size_t ws_size,
                              hipStream_t stream) {
  const float* x      = (const float*)d_in[0];
  const int*   pos    = (const int*)d_in[1];
  const float* w_qkv  = (const float*)d_in[2];
  const float* w_o    = (const float*)d_in[3];
  const float* qnw    = (const float*)d_in[4];
  const float* knw    = (const float*)d_in[5];
  float* out = (float*)d_out;

  char* ws = (char*)d_ws;
  const size_t MB = 1024 * 1024;
  unsigned short* x_bf   = (unsigned short*)(ws + 0);        // 8 MB  [2048][2048]
  unsigned short* Ob     = (unsigned short*)(ws + 0);        // reuses x_bf after GEMM1
  unsigned short* wqkv_t = (unsigned short*)(ws + 8 * MB);   // 16 MB [4096][2048]
  unsigned short* wo_t   = (unsigned short*)(ws + 24 * MB);  // 8 MB  [2048][2048]
  float*          qkv    = (float*)(ws + 32 * MB);           // 32 MB [2048][4096]
  unsigned short* Qb     = (unsigned short*)(ws + 64 * MB);  // 8 MB  [16][2048][128]
  unsigned short* Kb     = (unsigned short*)(ws + 72 * MB);  // 4 MB  [8][2048][128] (swizzled)
  unsigned short* Vtg    = (unsigned short*)(ws + 76 * MB);  // 4 MB  [8][32][128][64] (transposed+swizzled)

  k_cvt_bf16<<<(T_SEQ * HID) / 1024, 256, 0, stream>>>(x, x_bf);
  k_transpose_cvt<<<dim3(QKV_N / 32, HID / 32), dim3(32, 8), 0, stream>>>(w_qkv, wqkv_t, HID, QKV_N);
  k_transpose_cvt<<<dim3(HID / 32, HID / 32), dim3(32, 8), 0, stream>>>(w_o, wo_t, HID, HID);
  k_gemm8<<<dim3(QKV_N / 256, T_SEQ / 128), 512, 0, stream>>>(x_bf, wqkv_t, qkv, T_SEQ, QKV_N, HID);
  k_normrope<<<dim3(24, T_SEQ), 64, 0, stream>>>(qkv, pos, qnw, knw, Qb, Kb);
  k_vt<<<dim3(32, NKVH), 256, 0, stream>>>(qkv, Vtg);
  k_attn<<<512, 256, 0, stream>>>(Qb, Kb, Vtg, Ob);
  k_gemm8<<<dim3(HID / 256, T_SEQ / 128), 512, 0, stream>>>(Ob, wo_t, out, T_SEQ, HID, HID);
}